// Round 2
// baseline (283.011 us; speedup 1.0000x reference)
//
#include <hip/hip_runtime.h>
#include <math.h>

#define SEQLEN 2048
#define DIN 2048
#define NH 32
#define NKV 8
#define HD 64
#define DQ (NH*HD)    // 2048
#define DKV (NKV*HD)  // 512

using u16 = unsigned short;
using u32 = unsigned int;
using bf16x8 = __attribute__((ext_vector_type(8))) __bf16;
using f32x4  = __attribute__((ext_vector_type(4))) float;

__device__ __forceinline__ u16 f2b(float f) {
    union { float f; u32 u; } x; x.f = f;
    u32 u = x.u;
    u32 r = (u + 0x7fffu + ((u >> 16) & 1u)) >> 16;   // RNE
    return (u16)r;
}
__device__ __forceinline__ u32 fbits(float f) {
    union { float f; u32 u; } x; x.f = f; return x.u;
}

// async global->LDS, 16B/lane; lds base wave-uniform, lane i writes i*16B.
__device__ __forceinline__ void gl2lds16(const u16* g, u16* l) {
    __builtin_amdgcn_global_load_lds(
        (const __attribute__((address_space(1))) void*)g,
        (__attribute__((address_space(3))) void*)l,
        16, 0, 0);
}

// --- 8-row x 64-k chunks (512 u16) for attention tiles ----------------------
// loading lane -> (row = lane&7, koct = lane>>3); elem (row,kk) at
// chunk*512 + (kk>>3)*64 + (row&7)*8 + (kk&7). Conflict-free b128 frag reads.
__device__ __forceinline__ int lds_off(int row, int kk0) {
    return (row >> 3) * 512 + (kk0 >> 3) * 64 + (row & 7) * 8;
}
// --- 16-row x 32-k chunks (512 u16) for GEMM tiles --------------------------
// loading lane -> (row = lane&15, koct = lane>>4); elem (row,kk) at
// chunk*512 + (kk>>3)*128 + (row&15)*8 + (kk&7).
__device__ __forceinline__ int lds_off32(int row, int kk0) {
    return (row >> 4) * 512 + (kk0 >> 3) * 128 + (row & 15) * 8;
}

// ---------------------------------------------------------------------------
// Fused prep: cast x -> bf16; transpose-cast wq/wk/wv (contiguous [3072][2048])
// and wo.
// ---------------------------------------------------------------------------
__global__ __launch_bounds__(256) void prep(const float* __restrict__ x,
                                            const float* __restrict__ wq,
                                            const float* __restrict__ wk,
                                            const float* __restrict__ wv,
                                            const float* __restrict__ wo,
                                            u16* __restrict__ xb,
                                            u16* __restrict__ wqkvT,
                                            u16* __restrict__ woT) {
    const int b = blockIdx.x;
    const int t = threadIdx.x;
    if (b < 4096) {
        int i = b * 1024 + t * 4;
        float4 v = *reinterpret_cast<const float4*>(&x[i]);
        ushort4 o;
        o.x = f2b(v.x); o.y = f2b(v.y); o.z = f2b(v.z); o.w = f2b(v.w);
        *reinterpret_cast<ushort4*>(&xb[i]) = o;
        return;
    }
    __shared__ float tile[32][33];
    int b2 = b - 4096;
    const float* src; u16* dst; int C, bx, by;
    if (b2 < 4096)      { src = wq; dst = wqkvT;                           C = 2048; bx = b2 & 63; by = b2 >> 6; }
    else if (b2 < 5120) { b2 -= 4096; src = wk; dst = wqkvT + (size_t)2048 * 2048; C = 512; bx = b2 & 15; by = b2 >> 4; }
    else if (b2 < 6144) { b2 -= 5120; src = wv; dst = wqkvT + (size_t)2560 * 2048; C = 512; bx = b2 & 15; by = b2 >> 4; }
    else                { b2 -= 6144; src = wo; dst = woT;                 C = 2048; bx = b2 & 63; by = b2 >> 6; }
    const int c0 = bx * 32, r0 = by * 32;
    const int tr = t >> 5, tc = t & 31;
    #pragma unroll
    for (int i = 0; i < 4; ++i)
        tile[tr + i * 8][tc] = src[(size_t)(r0 + tr + i * 8) * C + c0 + tc];
    __syncthreads();
    #pragma unroll
    for (int i = 0; i < 4; ++i)
        dst[(size_t)(c0 + tr + i * 8) * 2048 + r0 + tc] = f2b(tile[tc][tr + i * 8]);
}

// ---------------------------------------------------------------------------
// bf16 MFMA GEMM v5: BM=64, BN=128, BK=32, depth-3 prefetch (4 LDS buffers)
// with COUNTED vmcnt (T4): never drain to 0 in the main loop. Rationale
// (rocprof r1): occupancy fix alone (15->32%) did NOT help -- every K-step
// ended in an implicit s_waitcnt vmcnt(0) before s_barrier (__syncthreads
// lowering), exposing a full memory latency per 32-k step. Now stage(st) is
// waited on 3 iterations after issue (vmcnt(6): stages st+1,st+2 remain in
// flight ACROSS the barrier). Single raw s_barrier per step: reads of buf
// st-1 precede barrier(st) in program order, and stage(st+3) -- which
// overwrites buf (st-1)&3 -- is issued after it.
// 4 waves as 2x2; wave tile = 32 rows x 64 cols (acc[2][4]). Wave's 64-col
// strip = one head is preserved for the MODE 1 epilogue: fused RMSNorm+RoPE
// for Q/K; V stored TRANSPOSED with columns interleaved within each 64-seq
// block:
//   pos(kv) = (b4*2 + (kt4>>1))*8 + (kt4&1)*4 + r,  kt4=kv>>4, b4=(kv>>2)&3,
// so attention's PV uses full-K=32 MFMAs with single b128 V reads.
// ---------------------------------------------------------------------------
template<int MODE>
__global__ __launch_bounds__(256) void gemm_glds(const u16* __restrict__ A,
                                                 const u16* __restrict__ Bt,
                                                 float* __restrict__ Cf,
                                                 u16* __restrict__ Qb,
                                                 u16* __restrict__ Kb,
                                                 u16* __restrict__ VtG,
                                                 const float* __restrict__ cosb,
                                                 const float* __restrict__ sinb,
                                                 const float* __restrict__ qnw,
                                                 const float* __restrict__ knw,
                                                 int M, int N, int K) {
    __shared__ u16 As[4][64 * 32];    // 4 bufs x 4 KB
    __shared__ u16 Bs[4][128 * 32];   // 4 bufs x 8 KB   (48 KB total)
    const int t = threadIdx.x;
    const int w = t >> 6, lane = t & 63, quad = lane >> 4, l15 = lane & 15;
    const int m0 = blockIdx.y * 64, n0 = blockIdx.x * 128;
    const int wr = (w >> 1) * 32, wc = (w & 1) * 64;
    const int srow = lane & 15, skoct = (lane >> 4) * 8;

    f32x4 acc[2][4];
    #pragma unroll
    for (int mt = 0; mt < 2; ++mt)
        #pragma unroll
        for (int nt = 0; nt < 4; ++nt)
            #pragma unroll
            for (int r = 0; r < 4; ++r) acc[mt][nt][r] = 0.0f;

    // 3 loads/lane per stage: A 1 chunk/wave, B 2 chunks/wave.
    auto stage = [&](int buf, int st) {
        const int k0 = st << 5;
        gl2lds16(A + (size_t)(m0 + w * 16 + srow) * K + k0 + skoct, &As[buf][w * 512]);
        #pragma unroll
        for (int i = 0; i < 2; ++i) {
            int c = w * 2 + i;
            gl2lds16(Bt + (size_t)(n0 + c * 16 + srow) * K + k0 + skoct, &Bs[buf][c * 512]);
        }
    };

    const int nsteps = K >> 5;
    stage(0, 0);
    if (nsteps > 1) stage(1, 1);
    if (nsteps > 2) stage(2, 2);

    for (int st = 0; st < nsteps; ++st) {
        const int rem = nsteps - 1 - st;
        // Retire stage(st) only; keep stages st+1, st+2 in flight across the
        // barrier (3 loads each).
        if (rem >= 2)      asm volatile("s_waitcnt vmcnt(6)" ::: "memory");
        else if (rem == 1) asm volatile("s_waitcnt vmcnt(3)" ::: "memory");
        else               asm volatile("s_waitcnt vmcnt(0)" ::: "memory");
        __builtin_amdgcn_s_barrier();
        asm volatile("" ::: "memory");       // no ds_read hoist above barrier
        if (rem >= 3) stage((st + 3) & 3, st + 3);   // overwrites buf (st-1)&3

        const int buf = st & 3;
        const int kk0 = quad * 8;
        bf16x8 a[2], b[4];
        #pragma unroll
        for (int mt = 0; mt < 2; ++mt)
            a[mt] = *reinterpret_cast<const bf16x8*>(&As[buf][lds_off32(wr + mt * 16 + l15, kk0)]);
        #pragma unroll
        for (int nt = 0; nt < 4; ++nt)
            b[nt] = *reinterpret_cast<const bf16x8*>(&Bs[buf][lds_off32(wc + nt * 16 + l15, kk0)]);
        #pragma unroll
        for (int mt = 0; mt < 2; ++mt)
            #pragma unroll
            for (int nt = 0; nt < 4; ++nt)
                acc[mt][nt] = __builtin_amdgcn_mfma_f32_16x16x32_bf16(a[mt], b[nt], acc[mt][nt], 0, 0, 0);
    }

    if (MODE == 0) {
        #pragma unroll
        for (int mt = 0; mt < 2; ++mt)
            #pragma unroll
            for (int nt = 0; nt < 4; ++nt) {
                const int rb  = m0 + wr + mt * 16 + quad * 4;
                const int col = n0 + wc + nt * 16 + l15;
                #pragma unroll
                for (int r = 0; r < 4; ++r)
                    Cf[(size_t)(rb + r) * N + col] = acc[mt][nt][r];
            }
        return;
    }

    // ---- MODE 1 epilogue: wave strip = one head ----
    const int hb = n0 + wc;
    if (hb >= 2560) {                      // V: transposed, interleaved columns
        #pragma unroll
        for (int mt = 0; mt < 2; ++mt) {
            const int rb  = m0 + wr + mt * 16 + quad * 4;   // seq base (4-aligned)
            const int s64 = rb & 63;
            const int a4  = (s64 >> 4) & 3, b4 = (s64 >> 2) & 3;
            const int colp = (rb & ~63) + (b4 * 2 + (a4 >> 1)) * 8 + (a4 & 1) * 4;
            #pragma unroll
            for (int nt = 0; nt < 4; ++nt) {
                const int d = hb - 2560 + nt * 16 + l15;
                ushort4 o;
                o.x = f2b(acc[mt][nt][0]); o.y = f2b(acc[mt][nt][1]);
                o.z = f2b(acc[mt][nt][2]); o.w = f2b(acc[mt][nt][3]);
                *reinterpret_cast<ushort4*>(&VtG[(size_t)d * 2048 + colp]) = o;
            }
        }
        return;
    }

    const bool isQ = hb < 2048;
    const float* nw = isQ ? qnw : knw;
    float wv_[4];
    #pragma unroll
    for (int nt = 0; nt < 4; ++nt) wv_[nt] = nw[nt * 16 + l15];

    #pragma unroll
    for (int mt = 0; mt < 2; ++mt) {
        float s2[4] = {0.f, 0.f, 0.f, 0.f};
        #pragma unroll
        for (int nt = 0; nt < 4; ++nt)
            #pragma unroll
            for (int r = 0; r < 4; ++r) s2[r] += acc[mt][nt][r] * acc[mt][nt][r];
        #pragma unroll
        for (int off = 1; off < 16; off <<= 1)
            #pragma unroll
            for (int r = 0; r < 4; ++r) s2[r] += __shfl_xor(s2[r], off);

        float vn[4][4];
        #pragma unroll
        for (int r = 0; r < 4; ++r) {
            float rin = rsqrtf(s2[r] * (1.0f / 64.0f) + 1e-6f);
            #pragma unroll
            for (int nt = 0; nt < 4; ++nt) vn[nt][r] = acc[mt][nt][r] * rin * wv_[nt];
        }

        #pragma unroll
        for (int r = 0; r < 4; ++r) {
            const int s = m0 + wr + mt * 16 + quad * 4 + r;
            #pragma unroll
            for (int nt = 0; nt < 4; ++nt) {
                const int d = nt * 16 + l15;
                float c  = cosb[s * 64 + d];
                float sn = sinb[s * 64 + d];
                float sgn = (nt < 2) ? -1.0f : 1.0f;     // rotate_half
                float res = vn[nt][r] * c + sgn * vn[nt ^ 2][r] * sn;
                if (isQ) {
                    res *= 0.18033688f;                   // 0.125 * log2(e)
                    Qb[(size_t)s * 2048 + hb + d] = f2b(res);
                } else {
                    Kb[(size_t)s * 512 + hb - 2048 + d] = f2b(res);
                }
            }
        }
    }
}

// ---------------------------------------------------------------------------
// MFMA flash attention v4. Grid 1024: qt = 31-(b>>5) (heavy first),
// kvh=(b&31)>>2, h=kvh*4+(b&3). Block = ONE head x 64 q-rows, wave w owns
// q-strip w*16..w*16+15. Double-buffered K/V prefetch. Fixed-shift softmax
// p=exp2(s-24). PV uses FULL K=32 MFMAs via column-interleaved V.
// ---------------------------------------------------------------------------
__global__ __launch_bounds__(256) void attn_fused(const u16* __restrict__ Qb,
                                                  const u16* __restrict__ Kb,
                                                  const u16* __restrict__ VtG,
                                                  u16* __restrict__ attnb) {
    __shared__ u16 Ks[2][4096];   // [buf][kv 64][d 64] swizzled 8x64 chunks
    __shared__ u16 Vt[2][4096];   // [buf][d 64][kv 64 interleaved] swizzled

    const int b    = blockIdx.x;
    const int qt   = 31 - (b >> 5);
    const int q0   = qt * 64;
    const int kvh  = (b & 31) >> 2;
    const int h    = kvh * 4 + (b & 3);
    const int t    = threadIdx.x;
    const int w    = t >> 6, lane = t & 63, quad = lane >> 4, l15 = lane & 15;
    const int srow = lane & 7, soct = (lane >> 3) * 8;
    const int qrow = q0 + w * 16 + l15;

    // Q B-frags (exp2-scaled)
    const u16* qr = Qb + (size_t)qrow * DQ + h * HD;
    bf16x8 qB[2];
    qB[0] = *reinterpret_cast<const bf16x8*>(qr + quad * 8);
    qB[1] = *reinterpret_cast<const bf16x8*>(qr + 32 + quad * 8);

    f32x4 o[4];
    #pragma unroll
    for (int dt = 0; dt < 4; ++dt)
        #pragma unroll
        for (int r = 0; r < 4; ++r) o[dt][r] = 0.0f;
    float lpart = 0.0f;

    auto stage = [&](int buf, int kt) {
        const int k0 = kt * 64;
        #pragma unroll
        for (int i = 0; i < 2; ++i) {
            int c = w * 2 + i;
            gl2lds16(Kb  + (size_t)(k0 + c * 8 + srow) * DKV + kvh * HD + soct, &Ks[buf][c * 512]);
            gl2lds16(VtG + (size_t)(kvh * HD + c * 8 + srow) * 2048 + k0 + soct, &Vt[buf][c * 512]);
        }
    };

    stage(0, 0);
    for (int kt = 0; kt <= qt; ++kt) {
        const int buf = kt & 1;
        __syncthreads();
        if (kt < qt) stage(buf ^ 1, kt + 1);
        const u16* ksb = Ks[buf];
        const u16* vtb = Vt[buf];

        // S^T = K . Q^T  (16 q x 64 kv per wave)
        f32x4 s[4];
        #pragma unroll
        for (int kt4 = 0; kt4 < 4; ++kt4)
            #pragma unroll
            for (int r = 0; r < 4; ++r) s[kt4][r] = 0.0f;
        #pragma unroll
        for (int ks = 0; ks < 2; ++ks) {
            const int kk0 = ks * 32 + quad * 8;
            #pragma unroll
            for (int kt4 = 0; kt4 < 4; ++kt4) {
                bf16x8 ka = *reinterpret_cast<const bf16x8*>(&ksb[lds_off(kt4 * 16 + l15, kk0)]);
                s[kt4] = __builtin_amdgcn_mfma_f32_16x16x32_bf16(ka, qB[ks], s[kt4], 0, 0, 0);
            }
        }

        if (kt == qt) {   // wave-uniform: only the diagonal tile masks
            const int qi = w * 16 + l15;   // q index within the 64-tile
            #pragma unroll
            for (int kt4 = 0; kt4 < 4; ++kt4)
                #pragma unroll
                for (int r = 0; r < 4; ++r)
                    if ((kt4 * 16 + quad * 4 + r) > qi) s[kt4][r] = -1e30f;
        }

        // exp2 + pack P^T B-frags
        u32 pb[4][2];
        #pragma unroll
        for (int kt4 = 0; kt4 < 4; ++kt4) {
            float p[4];
            #pragma unroll
            for (int r = 0; r < 4; ++r) {
                p[r] = exp2f(s[kt4][r] - 24.0f);
                lpart += p[r];
            }
            pb[kt4][0] = __builtin_amdgcn_perm(fbits(p[1]), fbits(p[0]), 0x07060302u);
            pb[kt4][1] = __builtin_amdgcn_perm(fbits(p[3]), fbits(p[2]), 0x07060302u);
        }

        // O^T += V^T . P^T : 2 pairs x 4 dt, full-K=32 MFMAs
        #pragma unroll
        for (int pair = 0; pair < 2; ++pair) {
            union { bf16x8 v; u32 u[4]; } pu;
            pu.u[0] = pb[pair * 2][0];     pu.u[1] = pb[pair * 2][1];
            pu.u[2] = pb[pair * 2 + 1][0]; pu.u[3] = pb[pair * 2 + 1][1];
            const int kk0 = (quad * 2 + pair) * 8;   // interleaved V column octet
            #pragma unroll
            for (int dt = 0; dt < 4; ++dt) {
                bf16x8 va = *reinterpret_cast<const bf16x8*>(&vtb[lds_off(dt * 16 + l15, kk0)]);
                o[dt] = __builtin_amdgcn_mfma_f32_16x16x32_bf16(va, pu.v, o[dt], 0, 0, 0);
            }
        }
    }

    lpart += __shfl_xor(lpart, 16);
    lpart += __shfl_xor(lpart, 32);
    float inv = 1.0f / lpart;

    #pragma unroll
    for (int dt = 0; dt < 4; ++dt) {
        ushort4 ov;
        ov.x = f2b(o[dt][0] * inv);
        ov.y = f2b(o[dt][1] * inv);
        ov.z = f2b(o[dt][2] * inv);
        ov.w = f2b(o[dt][3] * inv);
        *reinterpret_cast<ushort4*>(attnb + (size_t)qrow * DQ + h * HD + dt * 16 + quad * 4) = ov;
    }
}

// ---------------------------------------------------------------------------
extern "C" void kernel_launch(void* const* d_in, const int* in_sizes, int n_in,
                              void* d_out, int out_size, void* d_ws, size_t ws_size,
                              hipStream_t stream) {
    const float* x    = (const float*)d_in[0];
    const float* cosb = (const float*)d_in[1];
    const float* sinb = (const float*)d_in[2];
    const float* wq   = (const float*)d_in[3];
    const float* wk   = (const float*)d_in[4];
    const float* wv   = (const float*)d_in[5];
    const float* wo   = (const float*)d_in[6];
    const float* qnw  = (const float*)d_in[7];
    const float* knw  = (const float*)d_in[8];
    float* out = (float*)d_out;

    char* ws = (char*)d_ws;
    const size_t MB = 1024 * 1024;
    u16* xb    = (u16*)(ws + 0);          // 8 MB
    u16* wqkvT = (u16*)(ws + 8  * MB);    // 12 MB: [wq^T; wk^T; wv^T] [3072][2048]
    u16* woT   = (u16*)(ws + 20 * MB);    // 8 MB
    u16* Qb    = (u16*)(ws + 28 * MB);    // 8 MB
    u16* Kb    = (u16*)(ws + 36 * MB);    // 2 MB
    u16* VtG   = (u16*)(ws + 38 * MB);    // 2 MB  [512][2048] col-interleaved
    u16* attnb = (u16*)(ws + 40 * MB);    // 8 MB

    // 1) prep: cast x + weight transposes
    prep<<<14336, 256, 0, stream>>>(x, wq, wk, wv, wo, xb, wqkvT, woT);

    // 2) fused QKV projection w/ RMSNorm+RoPE epilogue (V transposed+interleaved)
    gemm_glds<1><<<dim3(3072 / 128, SEQLEN / 64), 256, 0, stream>>>(
        xb, wqkvT, nullptr, Qb, Kb, VtG, cosb, sinb, qnw, knw, SEQLEN, 3072, DIN);

    // 3) GQA causal flash attention v4
    attn_fused<<<1024, 256, 0, stream>>>(Qb, Kb, VtG, attnb);

    // 4) output projection
    gemm_glds<0><<<dim3(DIN / 128, SEQLEN / 64), 256, 0, stream>>>(
        attnb, woT, out, nullptr, nullptr, nullptr, nullptr, nullptr, nullptr, nullptr,
        SEQLEN, DIN, DQ);
}

// Round 3
// 277.291 us; speedup vs baseline: 1.0206x; 1.0206x over previous
//
#include <hip/hip_runtime.h>
#include <math.h>

#define SEQLEN 2048
#define DIN 2048
#define NH 32
#define NKV 8
#define HD 64
#define DQ (NH*HD)    // 2048
#define DKV (NKV*HD)  // 512

using u16 = unsigned short;
using u32 = unsigned int;
using bf16x8 = __attribute__((ext_vector_type(8))) __bf16;
using f32x4  = __attribute__((ext_vector_type(4))) float;

__device__ __forceinline__ u16 f2b(float f) {
    union { float f; u32 u; } x; x.f = f;
    u32 u = x.u;
    u32 r = (u + 0x7fffu + ((u >> 16) & 1u)) >> 16;   // RNE
    return (u16)r;
}
__device__ __forceinline__ u32 fbits(float f) {
    union { float f; u32 u; } x; x.f = f; return x.u;
}

// async global->LDS, 16B/lane; lds base wave-uniform, lane i writes i*16B.
__device__ __forceinline__ void gl2lds16(const u16* g, u16* l) {
    __builtin_amdgcn_global_load_lds(
        (const __attribute__((address_space(1))) void*)g,
        (__attribute__((address_space(3))) void*)l,
        16, 0, 0);
}

// --- 8-row x 64-k chunks (512 u16) for attention tiles ----------------------
// loading lane -> (row = lane&7, koct = lane>>3); elem (row,kk) at
// chunk*512 + (kk>>3)*64 + (row&7)*8 + (kk&7). Conflict-free b128 frag reads.
__device__ __forceinline__ int lds_off(int row, int kk0) {
    return (row >> 3) * 512 + (kk0 >> 3) * 64 + (row & 7) * 8;
}
// --- 16-row x 32-k chunks (512 u16) for GEMM tiles --------------------------
// loading lane -> (row = lane&15, koct = lane>>4); elem (row,kk) at
// chunk*512 + (kk>>3)*128 + (row&15)*8 + (kk&7).
__device__ __forceinline__ int lds_off32(int row, int kk0) {
    return (row >> 4) * 512 + (kk0 >> 3) * 128 + (row & 15) * 8;
}

// ---------------------------------------------------------------------------
// Fused prep: cast x -> bf16; transpose-cast wq/wk/wv (contiguous [3072][2048])
// and wo.
// ---------------------------------------------------------------------------
__global__ __launch_bounds__(256) void prep(const float* __restrict__ x,
                                            const float* __restrict__ wq,
                                            const float* __restrict__ wk,
                                            const float* __restrict__ wv,
                                            const float* __restrict__ wo,
                                            u16* __restrict__ xb,
                                            u16* __restrict__ wqkvT,
                                            u16* __restrict__ woT) {
    const int b = blockIdx.x;
    const int t = threadIdx.x;
    if (b < 4096) {
        int i = b * 1024 + t * 4;
        float4 v = *reinterpret_cast<const float4*>(&x[i]);
        ushort4 o;
        o.x = f2b(v.x); o.y = f2b(v.y); o.z = f2b(v.z); o.w = f2b(v.w);
        *reinterpret_cast<ushort4*>(&xb[i]) = o;
        return;
    }
    __shared__ float tile[32][33];
    int b2 = b - 4096;
    const float* src; u16* dst; int C, bx, by;
    if (b2 < 4096)      { src = wq; dst = wqkvT;                           C = 2048; bx = b2 & 63; by = b2 >> 6; }
    else if (b2 < 5120) { b2 -= 4096; src = wk; dst = wqkvT + (size_t)2048 * 2048; C = 512; bx = b2 & 15; by = b2 >> 4; }
    else if (b2 < 6144) { b2 -= 5120; src = wv; dst = wqkvT + (size_t)2560 * 2048; C = 512; bx = b2 & 15; by = b2 >> 4; }
    else                { b2 -= 6144; src = wo; dst = woT;                 C = 2048; bx = b2 & 63; by = b2 >> 6; }
    const int c0 = bx * 32, r0 = by * 32;
    const int tr = t >> 5, tc = t & 31;
    #pragma unroll
    for (int i = 0; i < 4; ++i)
        tile[tr + i * 8][tc] = src[(size_t)(r0 + tr + i * 8) * C + c0 + tc];
    __syncthreads();
    #pragma unroll
    for (int i = 0; i < 4; ++i)
        dst[(size_t)(c0 + tr + i * 8) * 2048 + r0 + tc] = f2b(tile[tc][tr + i * 8]);
}

// ---------------------------------------------------------------------------
// bf16 MFMA GEMM v6: BM=BN=128, BK=32. Lessons from r0-r2: 128x128 w/ 16
// MFMA/step (r0, 73us) beat BM=64 w/ 8 MFMA/step (r1 85us / r2-counted 78us)
// -- the per-step compute phase must be thick enough; counted vmcnt alone on
// a thin step is LDS/issue-bound. v6 = thick step (64x64/wave, 16 MFMA + 8
// b128 ds_read) + depth-3 counted-vmcnt pipeline (4 LDS bufs, stages
// st+1..st+3 in flight ACROSS the barrier; never vmcnt(0) mid-loop) + XCD
// swizzle (contiguous logical-tile chunk per XCD -> A-panel L2 locality;
// nwg%8==0 for both grids). Single raw s_barrier per step: reads of buf st-1
// precede barrier(st); stage(st+3) overwriting buf (st-1)&3 issues after it.
// MODE 0: fp32 C. MODE 1: QKV epilogue -- wave's 64-col strip is one head:
// fused RMSNorm+RoPE for Q/K; V stored TRANSPOSED, columns interleaved within
// each 64-seq block:
//   pos(kv) = (b4*2 + (kt4>>1))*8 + (kt4&1)*4 + r,  kt4=kv>>4, b4=(kv>>2)&3,
// so attention's PV uses full-K=32 MFMAs with single b128 V reads.
// ---------------------------------------------------------------------------
template<int MODE>
__global__ __launch_bounds__(256) void gemm_glds(const u16* __restrict__ A,
                                                 const u16* __restrict__ Bt,
                                                 float* __restrict__ Cf,
                                                 u16* __restrict__ Qb,
                                                 u16* __restrict__ Kb,
                                                 u16* __restrict__ VtG,
                                                 const float* __restrict__ cosb,
                                                 const float* __restrict__ sinb,
                                                 const float* __restrict__ qnw,
                                                 const float* __restrict__ knw,
                                                 int M, int N, int K) {
    __shared__ u16 As[4][128 * 32];   // 4 bufs x 8 KB
    __shared__ u16 Bs[4][128 * 32];   // 4 bufs x 8 KB   (64 KB total)
    const int t = threadIdx.x;
    const int w = t >> 6, lane = t & 63, quad = lane >> 4, l15 = lane & 15;

    // XCD-aware swizzle: hw dispatch id -> logical tile, 8 contiguous chunks.
    const int gx  = gridDim.x;
    const int id  = blockIdx.y * gx + blockIdx.x;
    const int cpx = (gx * gridDim.y) >> 3;     // nwg % 8 == 0
    const int swz = (id & 7) * cpx + (id >> 3);
    const int m0 = (swz / gx) * 128, n0 = (swz % gx) * 128;

    const int wr = (w >> 1) * 64, wc = (w & 1) * 64;
    const int srow = lane & 15, skoct = (lane >> 4) * 8;

    f32x4 acc[4][4];
    #pragma unroll
    for (int mt = 0; mt < 4; ++mt)
        #pragma unroll
        for (int nt = 0; nt < 4; ++nt)
            #pragma unroll
            for (int r = 0; r < 4; ++r) acc[mt][nt][r] = 0.0f;

    // 4 loads/lane per stage: A 2 chunks/wave + B 2 chunks/wave.
    auto stage = [&](int buf, int st) {
        const int k0 = st << 5;
        #pragma unroll
        for (int i = 0; i < 2; ++i) {
            int c = w * 2 + i;
            gl2lds16(A  + (size_t)(m0 + c * 16 + srow) * K + k0 + skoct, &As[buf][c * 512]);
            gl2lds16(Bt + (size_t)(n0 + c * 16 + srow) * K + k0 + skoct, &Bs[buf][c * 512]);
        }
    };

    const int nsteps = K >> 5;
    stage(0, 0);
    if (nsteps > 1) stage(1, 1);
    if (nsteps > 2) stage(2, 2);

    for (int st = 0; st < nsteps; ++st) {
        const int rem = nsteps - 1 - st;
        // Retire stage(st) only; stages st+1, st+2 (4 loads each) stay in
        // flight across the barrier.
        if (rem >= 2)      asm volatile("s_waitcnt vmcnt(8)" ::: "memory");
        else if (rem == 1) asm volatile("s_waitcnt vmcnt(4)" ::: "memory");
        else               asm volatile("s_waitcnt vmcnt(0)" ::: "memory");
        __builtin_amdgcn_s_barrier();
        asm volatile("" ::: "memory");       // no ds_read hoist above barrier
        if (rem >= 3) stage((st + 3) & 3, st + 3);   // overwrites buf (st-1)&3

        const int buf = st & 3;
        const int kk0 = quad * 8;
        bf16x8 a[4], b[4];
        #pragma unroll
        for (int mt = 0; mt < 4; ++mt)
            a[mt] = *reinterpret_cast<const bf16x8*>(&As[buf][lds_off32(wr + mt * 16 + l15, kk0)]);
        #pragma unroll
        for (int nt = 0; nt < 4; ++nt)
            b[nt] = *reinterpret_cast<const bf16x8*>(&Bs[buf][lds_off32(wc + nt * 16 + l15, kk0)]);
        #pragma unroll
        for (int mt = 0; mt < 4; ++mt)
            #pragma unroll
            for (int nt = 0; nt < 4; ++nt)
                acc[mt][nt] = __builtin_amdgcn_mfma_f32_16x16x32_bf16(a[mt], b[nt], acc[mt][nt], 0, 0, 0);
    }

    if (MODE == 0) {
        #pragma unroll
        for (int mt = 0; mt < 4; ++mt)
            #pragma unroll
            for (int nt = 0; nt < 4; ++nt) {
                const int rb  = m0 + wr + mt * 16 + quad * 4;
                const int col = n0 + wc + nt * 16 + l15;
                #pragma unroll
                for (int r = 0; r < 4; ++r)
                    Cf[(size_t)(rb + r) * N + col] = acc[mt][nt][r];
            }
        return;
    }

    // ---- MODE 1 epilogue: wave strip = one head ----
    const int hb = n0 + wc;
    if (hb >= 2560) {                      // V: transposed, interleaved columns
        #pragma unroll
        for (int mt = 0; mt < 4; ++mt) {
            const int rb  = m0 + wr + mt * 16 + quad * 4;   // seq base (4-aligned)
            const int s64 = rb & 63;
            const int a4  = (s64 >> 4) & 3, b4 = (s64 >> 2) & 3;
            const int colp = (rb & ~63) + (b4 * 2 + (a4 >> 1)) * 8 + (a4 & 1) * 4;
            #pragma unroll
            for (int nt = 0; nt < 4; ++nt) {
                const int d = hb - 2560 + nt * 16 + l15;
                ushort4 o;
                o.x = f2b(acc[mt][nt][0]); o.y = f2b(acc[mt][nt][1]);
                o.z = f2b(acc[mt][nt][2]); o.w = f2b(acc[mt][nt][3]);
                *reinterpret_cast<ushort4*>(&VtG[(size_t)d * 2048 + colp]) = o;
            }
        }
        return;
    }

    const bool isQ = hb < 2048;
    const float* nw = isQ ? qnw : knw;
    float wv_[4];
    #pragma unroll
    for (int nt = 0; nt < 4; ++nt) wv_[nt] = nw[nt * 16 + l15];

    #pragma unroll
    for (int mt = 0; mt < 4; ++mt) {
        float s2[4] = {0.f, 0.f, 0.f, 0.f};
        #pragma unroll
        for (int nt = 0; nt < 4; ++nt)
            #pragma unroll
            for (int r = 0; r < 4; ++r) s2[r] += acc[mt][nt][r] * acc[mt][nt][r];
        #pragma unroll
        for (int off = 1; off < 16; off <<= 1)
            #pragma unroll
            for (int r = 0; r < 4; ++r) s2[r] += __shfl_xor(s2[r], off);

        float vn[4][4];
        #pragma unroll
        for (int r = 0; r < 4; ++r) {
            float rin = rsqrtf(s2[r] * (1.0f / 64.0f) + 1e-6f);
            #pragma unroll
            for (int nt = 0; nt < 4; ++nt) vn[nt][r] = acc[mt][nt][r] * rin * wv_[nt];
        }

        #pragma unroll
        for (int r = 0; r < 4; ++r) {
            const int s = m0 + wr + mt * 16 + quad * 4 + r;
            #pragma unroll
            for (int nt = 0; nt < 4; ++nt) {
                const int d = nt * 16 + l15;
                float c  = cosb[s * 64 + d];
                float sn = sinb[s * 64 + d];
                float sgn = (nt < 2) ? -1.0f : 1.0f;     // rotate_half
                float res = vn[nt][r] * c + sgn * vn[nt ^ 2][r] * sn;
                if (isQ) {
                    res *= 0.18033688f;                   // 0.125 * log2(e)
                    Qb[(size_t)s * 2048 + hb + d] = f2b(res);
                } else {
                    Kb[(size_t)s * 512 + hb - 2048 + d] = f2b(res);
                }
            }
        }
    }
}

// ---------------------------------------------------------------------------
// MFMA flash attention v5: counted-vmcnt depth-2 pipeline (3 K/V buffers;
// stage kt+1 stays in flight across the barrier; vmcnt(0) only on the last
// step) + kvh-major XCD map: kvh = b&7 == XCD under round-robin dispatch, so
// each XCD streams exactly ONE kv-head's K/V (256+256 KB, L2-resident).
// qt = 31-(b>>5) keeps heavy-first ordering. Block = ONE head x 64 q-rows,
// wave w owns q-strip w*16..w*16+15. Fixed-shift softmax p=exp2(s-24).
// PV uses FULL K=32 MFMAs via column-interleaved V.
// ---------------------------------------------------------------------------
__global__ __launch_bounds__(256) void attn_fused(const u16* __restrict__ Qb,
                                                  const u16* __restrict__ Kb,
                                                  const u16* __restrict__ VtG,
                                                  u16* __restrict__ attnb) {
    __shared__ u16 Ks[3][4096];   // [buf][kv 64][d 64] swizzled 8x64 chunks
    __shared__ u16 Vt[3][4096];   // [buf][d 64][kv 64 interleaved] swizzled

    const int b    = blockIdx.x;
    const int kvh  = b & 7;                    // == XCD (round-robin)
    const int qt   = 31 - (b >> 5);            // heavy-first
    const int q0   = qt * 64;
    const int h    = kvh * 4 + ((b >> 3) & 3);
    const int t    = threadIdx.x;
    const int w    = t >> 6, lane = t & 63, quad = lane >> 4, l15 = lane & 15;
    const int srow = lane & 7, soct = (lane >> 3) * 8;
    const int qrow = q0 + w * 16 + l15;

    // Q B-frags (exp2-scaled)
    const u16* qr = Qb + (size_t)qrow * DQ + h * HD;
    bf16x8 qB[2];
    qB[0] = *reinterpret_cast<const bf16x8*>(qr + quad * 8);
    qB[1] = *reinterpret_cast<const bf16x8*>(qr + 32 + quad * 8);

    f32x4 o[4];
    #pragma unroll
    for (int dt = 0; dt < 4; ++dt)
        #pragma unroll
        for (int r = 0; r < 4; ++r) o[dt][r] = 0.0f;
    float lpart = 0.0f;

    auto stage = [&](int buf, int kt) {
        const int k0 = kt * 64;
        #pragma unroll
        for (int i = 0; i < 2; ++i) {
            int c = w * 2 + i;
            gl2lds16(Kb  + (size_t)(k0 + c * 8 + srow) * DKV + kvh * HD + soct, &Ks[buf][c * 512]);
            gl2lds16(VtG + (size_t)(kvh * HD + c * 8 + srow) * 2048 + k0 + soct, &Vt[buf][c * 512]);
        }
    };

    stage(0, 0);
    stage(1, 1);          // harmless over-stage when qt==0 (valid memory)
    int cur = 0;
    for (int kt = 0; kt <= qt; ++kt) {
        // Retire stage(kt) (4 loads); stage(kt+1) stays in flight.
        if (kt < qt) asm volatile("s_waitcnt vmcnt(4)" ::: "memory");
        else         asm volatile("s_waitcnt vmcnt(0)" ::: "memory");
        __builtin_amdgcn_s_barrier();
        asm volatile("" ::: "memory");
        if (kt + 2 <= qt) {
            int tgt = (cur == 0) ? 2 : cur - 1;   // = (kt+2)%3, read at kt-1
            stage(tgt, kt + 2);
        }
        const u16* ksb = Ks[cur];
        const u16* vtb = Vt[cur];

        // S^T = K . Q^T  (16 q x 64 kv per wave)
        f32x4 s[4];
        #pragma unroll
        for (int kt4 = 0; kt4 < 4; ++kt4)
            #pragma unroll
            for (int r = 0; r < 4; ++r) s[kt4][r] = 0.0f;
        #pragma unroll
        for (int ks = 0; ks < 2; ++ks) {
            const int kk0 = ks * 32 + quad * 8;
            #pragma unroll
            for (int kt4 = 0; kt4 < 4; ++kt4) {
                bf16x8 ka = *reinterpret_cast<const bf16x8*>(&ksb[lds_off(kt4 * 16 + l15, kk0)]);
                s[kt4] = __builtin_amdgcn_mfma_f32_16x16x32_bf16(ka, qB[ks], s[kt4], 0, 0, 0);
            }
        }

        if (kt == qt) {   // wave-uniform: only the diagonal tile masks
            const int qi = w * 16 + l15;   // q index within the 64-tile
            #pragma unroll
            for (int kt4 = 0; kt4 < 4; ++kt4)
                #pragma unroll
                for (int r = 0; r < 4; ++r)
                    if ((kt4 * 16 + quad * 4 + r) > qi) s[kt4][r] = -1e30f;
        }

        // exp2 + pack P^T B-frags
        u32 pb[4][2];
        #pragma unroll
        for (int kt4 = 0; kt4 < 4; ++kt4) {
            float p[4];
            #pragma unroll
            for (int r = 0; r < 4; ++r) {
                p[r] = exp2f(s[kt4][r] - 24.0f);
                lpart += p[r];
            }
            pb[kt4][0] = __builtin_amdgcn_perm(fbits(p[1]), fbits(p[0]), 0x07060302u);
            pb[kt4][1] = __builtin_amdgcn_perm(fbits(p[3]), fbits(p[2]), 0x07060302u);
        }

        // O^T += V^T . P^T : 2 pairs x 4 dt, full-K=32 MFMAs
        #pragma unroll
        for (int pair = 0; pair < 2; ++pair) {
            union { bf16x8 v; u32 u[4]; } pu;
            pu.u[0] = pb[pair * 2][0];     pu.u[1] = pb[pair * 2][1];
            pu.u[2] = pb[pair * 2 + 1][0]; pu.u[3] = pb[pair * 2 + 1][1];
            const int kk0 = (quad * 2 + pair) * 8;   // interleaved V column octet
            #pragma unroll
            for (int dt = 0; dt < 4; ++dt) {
                bf16x8 va = *reinterpret_cast<const bf16x8*>(&vtb[lds_off(dt * 16 + l15, kk0)]);
                o[dt] = __builtin_amdgcn_mfma_f32_16x16x32_bf16(va, pu.v, o[dt], 0, 0, 0);
            }
        }

        cur = (cur == 2) ? 0 : cur + 1;
    }

    lpart += __shfl_xor(lpart, 16);
    lpart += __shfl_xor(lpart, 32);
    float inv = 1.0f / lpart;

    #pragma unroll
    for (int dt = 0; dt < 4; ++dt) {
        ushort4 ov;
        ov.x = f2b(o[dt][0] * inv);
        ov.y = f2b(o[dt][1] * inv);
        ov.z = f2b(o[dt][2] * inv);
        ov.w = f2b(o[dt][3] * inv);
        *reinterpret_cast<ushort4*>(attnb + (size_t)qrow * DQ + h * HD + dt * 16 + quad * 4) = ov;
    }
}

// ---------------------------------------------------------------------------
extern "C" void kernel_launch(void* const* d_in, const int* in_sizes, int n_in,
                              void* d_out, int out_size, void* d_ws, size_t ws_size,
                              hipStream_t stream) {
    const float* x    = (const float*)d_in[0];
    const float* cosb = (const float*)d_in[1];
    const float* sinb = (const float*)d_in[2];
    const float* wq   = (const float*)d_in[3];
    const float* wk   = (const float*)d_in[4];
    const float* wv   = (const float*)d_in[5];
    const float* wo   = (const float*)d_in[6];
    const float* qnw  = (const float*)d_in[7];
    const float* knw  = (const float*)d_in[8];
    float* out = (float*)d_out;

    char* ws = (char*)d_ws;
    const size_t MB = 1024 * 1024;
    u16* xb    = (u16*)(ws + 0);          // 8 MB
    u16* wqkvT = (u16*)(ws + 8  * MB);    // 12 MB: [wq^T; wk^T; wv^T] [3072][2048]
    u16* woT   = (u16*)(ws + 20 * MB);    // 8 MB
    u16* Qb    = (u16*)(ws + 28 * MB);    // 8 MB
    u16* Kb    = (u16*)(ws + 36 * MB);    // 2 MB
    u16* VtG   = (u16*)(ws + 38 * MB);    // 2 MB  [512][2048] col-interleaved
    u16* attnb = (u16*)(ws + 40 * MB);    // 8 MB

    // 1) prep: cast x + weight transposes
    prep<<<14336, 256, 0, stream>>>(x, wq, wk, wv, wo, xb, wqkvT, woT);

    // 2) fused QKV projection w/ RMSNorm+RoPE epilogue (V transposed+interleaved)
    //    grid 24x16 = 384 blocks (%8==0 for XCD swizzle)
    gemm_glds<1><<<dim3(3072 / 128, SEQLEN / 128), 256, 0, stream>>>(
        xb, wqkvT, nullptr, Qb, Kb, VtG, cosb, sinb, qnw, knw, SEQLEN, 3072, DIN);

    // 3) GQA causal flash attention v5 (kvh==XCD map)
    attn_fused<<<1024, 256, 0, stream>>>(Qb, Kb, VtG, attnb);

    // 4) output projection: grid 16x16 = 256 blocks (%8==0)
    gemm_glds<0><<<dim3(DIN / 128, SEQLEN / 128), 256, 0, stream>>>(
        attnb, woT, out, nullptr, nullptr, nullptr, nullptr, nullptr, nullptr, nullptr,
        SEQLEN, DIN, DQ);
}

// Round 4
// 270.551 us; speedup vs baseline: 1.0461x; 1.0249x over previous
//
#include <hip/hip_runtime.h>
#include <math.h>

#define SEQLEN 2048
#define DIN 2048
#define NH 32
#define NKV 8
#define HD 64
#define DQ (NH*HD)    // 2048
#define DKV (NKV*HD)  // 512

using u16 = unsigned short;
using u32 = unsigned int;
using bf16x8 = __attribute__((ext_vector_type(8))) __bf16;
using f32x4  = __attribute__((ext_vector_type(4))) float;

__device__ __forceinline__ u16 f2b(float f) {
    union { float f; u32 u; } x; x.f = f;
    u32 u = x.u;
    u32 r = (u + 0x7fffu + ((u >> 16) & 1u)) >> 16;   // RNE
    return (u16)r;
}
__device__ __forceinline__ u32 fbits(float f) {
    union { float f; u32 u; } x; x.f = f; return x.u;
}

// async global->LDS, 16B/lane; lds base wave-uniform, lane i writes i*16B.
__device__ __forceinline__ void gl2lds16(const u16* g, u16* l) {
    __builtin_amdgcn_global_load_lds(
        (const __attribute__((address_space(1))) void*)g,
        (__attribute__((address_space(3))) void*)l,
        16, 0, 0);
}

// --- 8-row x 64-k chunks (512 u16) for attention tiles ----------------------
__device__ __forceinline__ int lds_off(int row, int kk0) {
    return (row >> 3) * 512 + (kk0 >> 3) * 64 + (row & 7) * 8;
}
// --- 16-row x 32-k chunks (512 u16) for GEMM tiles --------------------------
__device__ __forceinline__ int lds_off32(int row, int kk0) {
    return (row >> 4) * 512 + (kk0 >> 3) * 128 + (row & 15) * 8;
}

// ---------------------------------------------------------------------------
// Fused prep: cast x -> bf16; transpose-cast wq/wk/wv (contiguous [3072][2048])
// and wo.
// ---------------------------------------------------------------------------
__global__ __launch_bounds__(256) void prep(const float* __restrict__ x,
                                            const float* __restrict__ wq,
                                            const float* __restrict__ wk,
                                            const float* __restrict__ wv,
                                            const float* __restrict__ wo,
                                            u16* __restrict__ xb,
                                            u16* __restrict__ wqkvT,
                                            u16* __restrict__ woT) {
    const int b = blockIdx.x;
    const int t = threadIdx.x;
    if (b < 4096) {
        int i = b * 1024 + t * 4;
        float4 v = *reinterpret_cast<const float4*>(&x[i]);
        ushort4 o;
        o.x = f2b(v.x); o.y = f2b(v.y); o.z = f2b(v.z); o.w = f2b(v.w);
        *reinterpret_cast<ushort4*>(&xb[i]) = o;
        return;
    }
    __shared__ float tile[32][33];
    int b2 = b - 4096;
    const float* src; u16* dst; int C, bx, by;
    if (b2 < 4096)      { src = wq; dst = wqkvT;                           C = 2048; bx = b2 & 63; by = b2 >> 6; }
    else if (b2 < 5120) { b2 -= 4096; src = wk; dst = wqkvT + (size_t)2048 * 2048; C = 512; bx = b2 & 15; by = b2 >> 4; }
    else if (b2 < 6144) { b2 -= 5120; src = wv; dst = wqkvT + (size_t)2560 * 2048; C = 512; bx = b2 & 15; by = b2 >> 4; }
    else                { b2 -= 6144; src = wo; dst = woT;                 C = 2048; bx = b2 & 63; by = b2 >> 6; }
    const int c0 = bx * 32, r0 = by * 32;
    const int tr = t >> 5, tc = t & 31;
    #pragma unroll
    for (int i = 0; i < 4; ++i)
        tile[tr + i * 8][tc] = src[(size_t)(r0 + tr + i * 8) * C + c0 + tc];
    __syncthreads();
    #pragma unroll
    for (int i = 0; i < 4; ++i)
        dst[(size_t)(c0 + tr + i * 8) * 2048 + r0 + tc] = f2b(tile[tc][tr + i * 8]);
}

// ---------------------------------------------------------------------------
// QKV GEMM v7: SPLIT-K. Cross-round evidence (r0-r3): MfmaUtil pinned at
// ~12% regardless of counted-vmcnt / occupancy tweaks; m102 law says this
// structure needs ~3-4 blocks/CU of wave-level overlap (m114), and grid 384
// caps us at 1.5. Split-K=2: grid (24,16,2) = 768 blocks = 3/CU, each runs
// the r0-exact thick loop (BM=BN=128, BK=32, 2-buf, __syncthreads, 16 MFMA +
// 8 b128 per wave-step) over half of K, writing fp32 partials. Epilogue
// moved to qkv_reduce. No XCD swizzle (r3: it RAISED FETCH_SIZE 43->54MB).
// ---------------------------------------------------------------------------
__global__ __launch_bounds__(256) void gemm_splitk(const u16* __restrict__ A,
                                                   const u16* __restrict__ Bt,
                                                   float* __restrict__ P) {
    __shared__ u16 As[2][128 * 32];
    __shared__ u16 Bs[2][128 * 32];
    const int t = threadIdx.x;
    const int w = t >> 6, lane = t & 63, quad = lane >> 4, l15 = lane & 15;
    const int m0 = blockIdx.y * 128, n0 = blockIdx.x * 128;
    const int kb = blockIdx.z << 10;                 // 0 or 1024
    float* Cf = P + (size_t)blockIdx.z * (2048 * 3072);
    const int wr = (w >> 1) * 64, wc = (w & 1) * 64;
    const int srow = lane & 15, skoct = (lane >> 4) * 8;
    const int K = 2048, N = 3072;

    f32x4 acc[4][4];
    #pragma unroll
    for (int mt = 0; mt < 4; ++mt)
        #pragma unroll
        for (int nt = 0; nt < 4; ++nt)
            #pragma unroll
            for (int r = 0; r < 4; ++r) acc[mt][nt][r] = 0.0f;

    auto stage = [&](int buf, int k0) {
        #pragma unroll
        for (int i = 0; i < 2; ++i) {
            int c = w * 2 + i;
            gl2lds16(A  + (size_t)(m0 + c * 16 + srow) * K + kb + k0 + skoct, &As[buf][c * 512]);
            gl2lds16(Bt + (size_t)(n0 + c * 16 + srow) * K + kb + k0 + skoct, &Bs[buf][c * 512]);
        }
    };

    stage(0, 0);
    const int nsteps = 32;                           // K/2 / 32
    for (int st = 0; st < nsteps; ++st) {
        const int buf = st & 1;
        __syncthreads();
        if (st + 1 < nsteps) stage(buf ^ 1, (st + 1) << 5);
        const int kk0 = quad * 8;
        bf16x8 a[4], b[4];
        #pragma unroll
        for (int mt = 0; mt < 4; ++mt)
            a[mt] = *reinterpret_cast<const bf16x8*>(&As[buf][lds_off32(wr + mt * 16 + l15, kk0)]);
        #pragma unroll
        for (int nt = 0; nt < 4; ++nt)
            b[nt] = *reinterpret_cast<const bf16x8*>(&Bs[buf][lds_off32(wc + nt * 16 + l15, kk0)]);
        #pragma unroll
        for (int mt = 0; mt < 4; ++mt)
            #pragma unroll
            for (int nt = 0; nt < 4; ++nt)
                acc[mt][nt] = __builtin_amdgcn_mfma_f32_16x16x32_bf16(a[mt], b[nt], acc[mt][nt], 0, 0, 0);
    }

    #pragma unroll
    for (int mt = 0; mt < 4; ++mt)
        #pragma unroll
        for (int nt = 0; nt < 4; ++nt) {
            const int rb  = m0 + wr + mt * 16 + quad * 4;
            const int col = n0 + wc + nt * 16 + l15;
            #pragma unroll
            for (int r = 0; r < 4; ++r)
                Cf[(size_t)(rb + r) * N + col] = acc[mt][nt][r];
        }
}

// ---------------------------------------------------------------------------
// qkv_reduce: P0+P1 -> fused RMSNorm+RoPE (Q/K) or interleave-transpose (V).
// Grid (32 s-tiles, 48 heads), 256 thr. Thread t: row r=t>>2 (s0+r), d-chunk
// q=t&3 (16 d's). 4-lane groups share a row: shfl_xor 1,2 for the RMS sum;
// RoPE partner d^32 lives at lane t^2. Q pre-scaled by 0.125*log2(e) for the
// attn exp2 softmax. V heads: interleave cl(r) = bit-perm of r (bijective,
// matches the old MODE1 epilogue + attn PV layout), via an 8KB LDS transpose.
// ---------------------------------------------------------------------------
__global__ __launch_bounds__(256) void qkv_reduce(const float* __restrict__ P,
                                                  u16* __restrict__ Qb,
                                                  u16* __restrict__ Kb,
                                                  u16* __restrict__ VtG,
                                                  const float* __restrict__ cosb,
                                                  const float* __restrict__ sinb,
                                                  const float* __restrict__ qnw,
                                                  const float* __restrict__ knw) {
    __shared__ u16 Vl[64][64];
    const int s0 = blockIdx.x * 64;
    const int h  = blockIdx.y;                    // 0..31 Q, 32..39 K, 40..47 V
    const int t  = threadIdx.x;
    const int r  = t >> 2, q = t & 3;
    const int s  = s0 + r;

    const float* p0 = P + (size_t)s * 3072 + h * 64 + q * 16;
    const float* p1 = p0 + (size_t)2048 * 3072;
    float v[16];
    #pragma unroll
    for (int i = 0; i < 4; ++i) {
        float4 a = *reinterpret_cast<const float4*>(p0 + i * 4);
        float4 b = *reinterpret_cast<const float4*>(p1 + i * 4);
        v[i*4+0] = a.x + b.x; v[i*4+1] = a.y + b.y;
        v[i*4+2] = a.z + b.z; v[i*4+3] = a.w + b.w;
    }

    if (h >= 40) {                                // ---- V ----
        const int a4 = (r >> 4) & 3, b4 = (r >> 2) & 3;
        const int cl = (b4 * 2 + (a4 >> 1)) * 8 + (a4 & 1) * 4 + (r & 3);
        #pragma unroll
        for (int i = 0; i < 16; ++i) Vl[q * 16 + i][cl] = f2b(v[i]);
        __syncthreads();
        u16* dst = VtG + (size_t)((h - 40) * 64 + r) * 2048 + s0 + q * 16;
        #pragma unroll
        for (int i = 0; i < 4; ++i)
            *reinterpret_cast<ushort4*>(dst + i * 4) =
                *reinterpret_cast<const ushort4*>(&Vl[r][q * 16 + i * 4]);
        return;
    }

    const bool isQ = h < 32;
    const float* nw = isQ ? qnw : knw;
    float s2 = 0.0f;
    #pragma unroll
    for (int i = 0; i < 16; ++i) s2 += v[i] * v[i];
    s2 += __shfl_xor(s2, 1);
    s2 += __shfl_xor(s2, 2);
    const float rin = rsqrtf(s2 * (1.0f / 64.0f) + 1e-6f);

    float vn[16];
    #pragma unroll
    for (int i = 0; i < 16; ++i) vn[i] = v[i] * rin * nw[q * 16 + i];

    const float sgn = (q < 2) ? -1.0f : 1.0f;     // rotate_half sign
    float res[16];
    #pragma unroll
    for (int i = 0; i < 16; ++i) {
        const int d = q * 16 + i;
        float c  = cosb[s * 64 + d];
        float sn = sinb[s * 64 + d];
        float vp = __shfl_xor(vn[i], 2);          // partner d^32
        res[i] = vn[i] * c + sgn * vp * sn;
    }

    u16* dst;
    if (isQ) {
        #pragma unroll
        for (int i = 0; i < 16; ++i) res[i] *= 0.18033688f;   // 0.125*log2(e)
        dst = Qb + (size_t)s * 2048 + h * 64 + q * 16;
    } else {
        dst = Kb + (size_t)s * 512 + (h - 32) * 64 + q * 16;
    }
    #pragma unroll
    for (int i = 0; i < 4; ++i) {
        ushort4 o;
        o.x = f2b(res[i*4+0]); o.y = f2b(res[i*4+1]);
        o.z = f2b(res[i*4+2]); o.w = f2b(res[i*4+3]);
        *reinterpret_cast<ushort4*>(dst + i * 4) = o;
    }
}

// ---------------------------------------------------------------------------
// Out-projection GEMM: r1's measured-best config. BM=64, BN=128, BK=32,
// 2-buf __syncthreads, grid (16,32) = 512 blocks = 2/CU. Thin step but the
// grid fills; r1 showed this ~18us faster than 128^2 at 1/CU.
// ---------------------------------------------------------------------------
__global__ __launch_bounds__(256) void gemm_out(const u16* __restrict__ A,
                                                const u16* __restrict__ Bt,
                                                float* __restrict__ Cf) {
    __shared__ u16 As[2][64 * 32];
    __shared__ u16 Bs[2][128 * 32];
    const int t = threadIdx.x;
    const int w = t >> 6, lane = t & 63, quad = lane >> 4, l15 = lane & 15;
    const int m0 = blockIdx.y * 64, n0 = blockIdx.x * 128;
    const int wr = (w >> 1) * 32, wc = (w & 1) * 64;
    const int srow = lane & 15, skoct = (lane >> 4) * 8;
    const int K = 2048, N = 2048;

    f32x4 acc[2][4];
    #pragma unroll
    for (int mt = 0; mt < 2; ++mt)
        #pragma unroll
        for (int nt = 0; nt < 4; ++nt)
            #pragma unroll
            for (int r = 0; r < 4; ++r) acc[mt][nt][r] = 0.0f;

    auto stage = [&](int buf, int k0) {
        gl2lds16(A + (size_t)(m0 + w * 16 + srow) * K + k0 + skoct, &As[buf][w * 512]);
        #pragma unroll
        for (int i = 0; i < 2; ++i) {
            int c = w * 2 + i;
            gl2lds16(Bt + (size_t)(n0 + c * 16 + srow) * K + k0 + skoct, &Bs[buf][c * 512]);
        }
    };

    stage(0, 0);
    const int nsteps = K >> 5;
    for (int st = 0; st < nsteps; ++st) {
        const int buf = st & 1;
        __syncthreads();
        if (st + 1 < nsteps) stage(buf ^ 1, (st + 1) << 5);
        const int kk0 = quad * 8;
        bf16x8 a[2], b[4];
        #pragma unroll
        for (int mt = 0; mt < 2; ++mt)
            a[mt] = *reinterpret_cast<const bf16x8*>(&As[buf][lds_off32(wr + mt * 16 + l15, kk0)]);
        #pragma unroll
        for (int nt = 0; nt < 4; ++nt)
            b[nt] = *reinterpret_cast<const bf16x8*>(&Bs[buf][lds_off32(wc + nt * 16 + l15, kk0)]);
        #pragma unroll
        for (int mt = 0; mt < 2; ++mt)
            #pragma unroll
            for (int nt = 0; nt < 4; ++nt)
                acc[mt][nt] = __builtin_amdgcn_mfma_f32_16x16x32_bf16(a[mt], b[nt], acc[mt][nt], 0, 0, 0);
    }

    #pragma unroll
    for (int mt = 0; mt < 2; ++mt)
        #pragma unroll
        for (int nt = 0; nt < 4; ++nt) {
            const int rb  = m0 + wr + mt * 16 + quad * 4;
            const int col = n0 + wc + nt * 16 + l15;
            #pragma unroll
            for (int r = 0; r < 4; ++r)
                Cf[(size_t)(rb + r) * N + col] = acc[mt][nt][r];
        }
}

// ---------------------------------------------------------------------------
// MFMA flash attention v5 (unchanged from r3): counted-vmcnt depth-2 pipeline
// (3 K/V buffers) + kvh = b&7 (== XCD under round-robin) so each XCD streams
// one kv-head's K/V (L2-resident). qt = 31-(b>>5) heavy-first. Block = ONE
// head x 64 q-rows; wave w owns q-strip w*16..w*16+15. Fixed-shift softmax
// p=exp2(s-24). PV uses FULL K=32 MFMAs via column-interleaved V.
// ---------------------------------------------------------------------------
__global__ __launch_bounds__(256) void attn_fused(const u16* __restrict__ Qb,
                                                  const u16* __restrict__ Kb,
                                                  const u16* __restrict__ VtG,
                                                  u16* __restrict__ attnb) {
    __shared__ u16 Ks[3][4096];
    __shared__ u16 Vt[3][4096];

    const int b    = blockIdx.x;
    const int kvh  = b & 7;
    const int qt   = 31 - (b >> 5);
    const int q0   = qt * 64;
    const int h    = kvh * 4 + ((b >> 3) & 3);
    const int t    = threadIdx.x;
    const int w    = t >> 6, lane = t & 63, quad = lane >> 4, l15 = lane & 15;
    const int srow = lane & 7, soct = (lane >> 3) * 8;
    const int qrow = q0 + w * 16 + l15;

    const u16* qr = Qb + (size_t)qrow * DQ + h * HD;
    bf16x8 qB[2];
    qB[0] = *reinterpret_cast<const bf16x8*>(qr + quad * 8);
    qB[1] = *reinterpret_cast<const bf16x8*>(qr + 32 + quad * 8);

    f32x4 o[4];
    #pragma unroll
    for (int dt = 0; dt < 4; ++dt)
        #pragma unroll
        for (int r = 0; r < 4; ++r) o[dt][r] = 0.0f;
    float lpart = 0.0f;

    auto stage = [&](int buf, int kt) {
        const int k0 = kt * 64;
        #pragma unroll
        for (int i = 0; i < 2; ++i) {
            int c = w * 2 + i;
            gl2lds16(Kb  + (size_t)(k0 + c * 8 + srow) * DKV + kvh * HD + soct, &Ks[buf][c * 512]);
            gl2lds16(VtG + (size_t)(kvh * HD + c * 8 + srow) * 2048 + k0 + soct, &Vt[buf][c * 512]);
        }
    };

    stage(0, 0);
    stage(1, 1);
    int cur = 0;
    for (int kt = 0; kt <= qt; ++kt) {
        if (kt < qt) asm volatile("s_waitcnt vmcnt(4)" ::: "memory");
        else         asm volatile("s_waitcnt vmcnt(0)" ::: "memory");
        __builtin_amdgcn_s_barrier();
        asm volatile("" ::: "memory");
        if (kt + 2 <= qt) {
            int tgt = (cur == 0) ? 2 : cur - 1;
            stage(tgt, kt + 2);
        }
        const u16* ksb = Ks[cur];
        const u16* vtb = Vt[cur];

        f32x4 s[4];
        #pragma unroll
        for (int kt4 = 0; kt4 < 4; ++kt4)
            #pragma unroll
            for (int r = 0; r < 4; ++r) s[kt4][r] = 0.0f;
        #pragma unroll
        for (int ks = 0; ks < 2; ++ks) {
            const int kk0 = ks * 32 + quad * 8;
            #pragma unroll
            for (int kt4 = 0; kt4 < 4; ++kt4) {
                bf16x8 ka = *reinterpret_cast<const bf16x8*>(&ksb[lds_off(kt4 * 16 + l15, kk0)]);
                s[kt4] = __builtin_amdgcn_mfma_f32_16x16x32_bf16(ka, qB[ks], s[kt4], 0, 0, 0);
            }
        }

        if (kt == qt) {
            const int qi = w * 16 + l15;
            #pragma unroll
            for (int kt4 = 0; kt4 < 4; ++kt4)
                #pragma unroll
                for (int r = 0; r < 4; ++r)
                    if ((kt4 * 16 + quad * 4 + r) > qi) s[kt4][r] = -1e30f;
        }

        u32 pb[4][2];
        #pragma unroll
        for (int kt4 = 0; kt4 < 4; ++kt4) {
            float p[4];
            #pragma unroll
            for (int r = 0; r < 4; ++r) {
                p[r] = exp2f(s[kt4][r] - 24.0f);
                lpart += p[r];
            }
            pb[kt4][0] = __builtin_amdgcn_perm(fbits(p[1]), fbits(p[0]), 0x07060302u);
            pb[kt4][1] = __builtin_amdgcn_perm(fbits(p[3]), fbits(p[2]), 0x07060302u);
        }

        #pragma unroll
        for (int pair = 0; pair < 2; ++pair) {
            union { bf16x8 v; u32 u[4]; } pu;
            pu.u[0] = pb[pair * 2][0];     pu.u[1] = pb[pair * 2][1];
            pu.u[2] = pb[pair * 2 + 1][0]; pu.u[3] = pb[pair * 2 + 1][1];
            const int kk0 = (quad * 2 + pair) * 8;
            #pragma unroll
            for (int dt = 0; dt < 4; ++dt) {
                bf16x8 va = *reinterpret_cast<const bf16x8*>(&vtb[lds_off(dt * 16 + l15, kk0)]);
                o[dt] = __builtin_amdgcn_mfma_f32_16x16x32_bf16(va, pu.v, o[dt], 0, 0, 0);
            }
        }

        cur = (cur == 2) ? 0 : cur + 1;
    }

    lpart += __shfl_xor(lpart, 16);
    lpart += __shfl_xor(lpart, 32);
    float inv = 1.0f / lpart;

    #pragma unroll
    for (int dt = 0; dt < 4; ++dt) {
        ushort4 ov;
        ov.x = f2b(o[dt][0] * inv);
        ov.y = f2b(o[dt][1] * inv);
        ov.z = f2b(o[dt][2] * inv);
        ov.w = f2b(o[dt][3] * inv);
        *reinterpret_cast<ushort4*>(attnb + (size_t)qrow * DQ + h * HD + dt * 16 + quad * 4) = ov;
    }
}

// ---------------------------------------------------------------------------
extern "C" void kernel_launch(void* const* d_in, const int* in_sizes, int n_in,
                              void* d_out, int out_size, void* d_ws, size_t ws_size,
                              hipStream_t stream) {
    const float* x    = (const float*)d_in[0];
    const float* cosb = (const float*)d_in[1];
    const float* sinb = (const float*)d_in[2];
    const float* wq   = (const float*)d_in[3];
    const float* wk   = (const float*)d_in[4];
    const float* wv   = (const float*)d_in[5];
    const float* wo   = (const float*)d_in[6];
    const float* qnw  = (const float*)d_in[7];
    const float* knw  = (const float*)d_in[8];
    float* out = (float*)d_out;

    char* ws = (char*)d_ws;
    const size_t MB = 1024 * 1024;
    u16*   xb    = (u16*)(ws + 0);          // 8 MB
    u16*   wqkvT = (u16*)(ws + 8  * MB);    // 12 MB: [wq^T; wk^T; wv^T] [3072][2048]
    u16*   woT   = (u16*)(ws + 20 * MB);    // 8 MB
    u16*   Qb    = (u16*)(ws + 28 * MB);    // 8 MB
    u16*   Kb    = (u16*)(ws + 36 * MB);    // 2 MB
    u16*   VtG   = (u16*)(ws + 38 * MB);    // 2 MB  [512][2048] col-interleaved
    u16*   attnb = (u16*)(ws + 40 * MB);    // 8 MB (aliases head of Pq, which is
                                            //       dead after qkv_reduce)
    float* Pq    = (float*)(ws + 40 * MB);  // 2 x 24 MB fp32 QKV partials
                                            // total ws use: ~90.4 MB

    // 1) prep: cast x + weight transposes
    prep<<<14336, 256, 0, stream>>>(x, wq, wk, wv, wo, xb, wqkvT, woT);

    // 2a) QKV projection, split-K=2: 768 blocks = 3 blocks/CU (thick step)
    gemm_splitk<<<dim3(3072 / 128, SEQLEN / 128, 2), 256, 0, stream>>>(
        xb, wqkvT, Pq);

    // 2b) reduce + fused RMSNorm/RoPE/V-interleave epilogue
    qkv_reduce<<<dim3(SEQLEN / 64, 48), 256, 0, stream>>>(
        Pq, Qb, Kb, VtG, cosb, sinb, qnw, knw);

    // 3) GQA causal flash attention v5
    attn_fused<<<1024, 256, 0, stream>>>(Qb, Kb, VtG, attnb);

    // 4) output projection: BM=64, 512 blocks = 2 blocks/CU (r1 best)
    gemm_out<<<dim3(DIN / 128, SEQLEN / 64), 256, 0, stream>>>(
        attnb, woT, out);
}